// Round 1
// baseline (164.905 us; speedup 1.0000x reference)
//
#include <hip/hip_runtime.h>

#define BB 32
#define QQ 16384
#define GG 128
#define KK 32
#define NN 9
#define CAP 2048

typedef unsigned long long u64;
typedef unsigned int u32;

// packed ascending key: (float bits of nonneg key) << 32 | idx
// lexicographic u64 compare == (value asc, index asc) == jax top_k tie rule
__device__ __forceinline__ u64 pack_asc(float key, u32 idx) {
  return (((u64)__float_as_uint(key)) << 32) | (u64)idx;
}

// distance exactly as reference: sqrt(((dx^2+dy^2)+dz^2)+dw^2), no fma contraction
__device__ __forceinline__ float dist4(const float4 g, const float4 p) {
#pragma clang fp contract(off)
  float dx = g.x - p.x;
  float dy = g.y - p.y;
  float dz = g.z - p.z;
  float dw = g.w - p.w;
  float s = dx * dx + dy * dy;
  s = s + dz * dz;
  s = s + dw * dw;
  return sqrtf(s);
}

// IoU exactly as reference (cxcywh -> xyxy, clip, same op order)
__device__ __forceinline__ float iou_ref(const float4 g, const float4 p) {
#pragma clang fp contract(off)
  float gx1 = g.x - 0.5f * g.z, gy1 = g.y - 0.5f * g.w;
  float gx2 = g.x + 0.5f * g.z, gy2 = g.y + 0.5f * g.w;
  float px1 = p.x - 0.5f * p.z, py1 = p.y - 0.5f * p.w;
  float px2 = p.x + 0.5f * p.z, py2 = p.y + 0.5f * p.w;
  float ltx = fmaxf(gx1, px1), lty = fmaxf(gy1, py1);
  float rbx = fminf(gx2, px2), rby = fminf(gy2, py2);
  float wx = fmaxf(rbx - ltx, 0.0f), wy = fmaxf(rby - lty, 0.0f);
  float inter = wx * wy;
  float aa = (gx2 - gx1) * (gy2 - gy1);
  float ab = (px2 - px1) * (py2 - py1);
  return inter / ((aa + ab) - inter);
}

// full ascending bitonic sort across one 64-lane wave
__device__ __forceinline__ u64 bitonic64(u64 v, int lane) {
#pragma unroll
  for (int k = 2; k <= 64; k <<= 1) {
#pragma unroll
    for (int j = k >> 1; j > 0; j >>= 1) {
      u64 o = __shfl_xor(v, j, 64);
      bool up = ((lane & k) == 0);
      bool lower = ((lane & j) == 0);
      v = (lower == up) ? (v < o ? v : o) : (v > o ? v : o);
    }
  }
  return v;
}

__global__ __launch_bounds__(256) void atss_kernel(
    const float4* __restrict__ pred, const float4* __restrict__ gtb,
    int* __restrict__ out) {
  __shared__ u64 smin[256];
  __shared__ float ckey[CAP];
  __shared__ unsigned short cidx[CAP];
  __shared__ int kidx[KK];
  __shared__ int nCand;
  __shared__ float sU;

  const int t = threadIdx.x;
  const int g = blockIdx.x;
  const int b = blockIdx.y;
  if (t == 0) nCand = 0;

  const float4 gt = gtb[b * GG + g];
  const float4* pb = pred + (size_t)b * QQ;

  // ---- pass 1: per-thread packed min over 64 strided elements ----
  u64 lmin = ~0ull;
#pragma unroll 4
  for (int j = 0; j < QQ / 256; ++j) {
    int i = t + j * 256;
    float d = dist4(gt, pb[i]);
    u64 pk = pack_asc(d, (u32)i);
    lmin = pk < lmin ? pk : lmin;
  }
  smin[t] = lmin;
  __syncthreads();

  // ---- threshold U = 32nd smallest of 64 lane-merged thread-mins ----
  // >=32 distinct elements have d <= U, so collecting d <= U is a superset
  // of the true top-32.
  if (t < 64) {
    u64 a = smin[t];
    u64 c1 = smin[t + 64];
    a = c1 < a ? c1 : a;
    u64 c2 = smin[t + 128];
    a = c2 < a ? c2 : a;
    u64 c3 = smin[t + 192];
    a = c3 < a ? c3 : a;
    u64 srt = bitonic64(a, t);
    if (t == 31) sU = __uint_as_float((u32)(srt >> 32));
  }
  __syncthreads();

  // ---- pass 2: collect candidates with d <= U ----
  // threads whose own min is > U cannot contribute: skip their rescan
  const float U = sU;
  if (__uint_as_float((u32)(lmin >> 32)) <= U) {
    for (int j = 0; j < QQ / 256; ++j) {
      int i = t + j * 256;
      float d = dist4(gt, pb[i]);
      if (d <= U) {
        int pos = atomicAdd(&nCand, 1);
        if (pos < CAP) {
          ckey[pos] = d;
          cidx[pos] = (unsigned short)i;
        }
      }
    }
  }
  __syncthreads();

  const int n = nCand;  // guaranteed >= 32

  // ---- select top-32 by (d, idx) ascending -> kidx sorted like ref kidx ----
  if (n > CAP) {
    // pathological-only exact serial fallback
    if (t == 0) {
      u64 best[KK];
      for (int l = 0; l < KK; ++l) best[l] = ~0ull;
      for (int i = 0; i < QQ; ++i) {
        float d = dist4(gt, pb[i]);
        u64 pk = pack_asc(d, (u32)i);
        if (pk < best[KK - 1]) {
          int pos = KK - 1;
          while (pos > 0 && best[pos - 1] > pk) {
            best[pos] = best[pos - 1];
            --pos;
          }
          best[pos] = pk;
        }
      }
      for (int l = 0; l < KK; ++l) kidx[l] = (int)(best[l] & 0xFFFFFFFFull);
    }
  } else if (t < 64) {
    if (n <= 64) {
      // fast path (expected ~95%+): one wave bitonic sort
      u64 v = (t < n) ? pack_asc(ckey[t], (u32)cidx[t]) : ~0ull;
      u64 srt = bitonic64(v, t);
      if (t < KK) kidx[t] = (int)(srt & 0xFFFFFFFFull);
    } else {
      // 64 < n <= CAP: 32 rounds of wave-wide argmin extraction
      volatile float* vk = ckey;
      for (int sel = 0; sel < KK; ++sel) {
        u64 lm = ~0ull;
        int ls = -1;
        for (int s = t; s < n; s += 64) {
          float d = vk[s];
          u64 pk = pack_asc(d, (u32)cidx[s]);
          if (pk < lm) {
            lm = pk;
            ls = s;
          }
        }
        u64 w = lm;
#pragma unroll
        for (int j = 32; j > 0; j >>= 1) {
          u64 o = __shfl_xor(w, j, 64);
          w = o < w ? o : w;
        }
        if (lm == w && ls >= 0) {  // unique winner (idx unique)
          vk[ls] = __uint_as_float(0x7F800000u);  // mark used with +inf
          kidx[sel] = (int)(w & 0xFFFFFFFFull);
        }
      }
    }
  }
  __syncthreads();

  // ---- IoU of the 32 candidates, top-9 by (iou desc, position asc) ----
  if (t < 64) {
    u64 v = ~0ull;
    if (t < KK) {
      float iou = iou_ref(gt, pb[kidx[t]]);
      // ~bits(iou) is strictly decreasing in iou (iou >= 0): ascending sort
      // of packed == descending iou, ties -> lower K-position first
      v = (((u64)(~__float_as_uint(iou))) << 32) | (u64)t;
    }
    u64 srt = bitonic64(v, t);
    if (t < NN) {
      int pos = (int)(srt & 0xFFFFFFFFull);
      int base = (b * GG + g) * NN + t;
      out[base] = kidx[pos];                // pred_idx
      out[BB * GG * NN + base] = g;         // gt_idx
    }
  }
}

extern "C" void kernel_launch(void* const* d_in, const int* in_sizes, int n_in,
                              void* d_out, int out_size, void* d_ws, size_t ws_size,
                              hipStream_t stream) {
  (void)in_sizes;
  (void)n_in;
  (void)out_size;
  (void)d_ws;
  (void)ws_size;
  const float4* pred = (const float4*)d_in[0];  // [B, Q, 4] f32
  const float4* gt = (const float4*)d_in[1];    // [B, G, 4] f32
  int* out = (int*)d_out;                       // [2 * B * G * N] int32
  dim3 grid(GG, BB);
  atss_kernel<<<grid, 256, 0, stream>>>(pred, gt, out);
}

// Round 2
// 135.706 us; speedup vs baseline: 1.2152x; 1.2152x over previous
//
#include <hip/hip_runtime.h>

#define BB 32
#define QQ 16384
#define GG 128
#define KK 32
#define NN 9
#define CAP 2048

typedef unsigned long long u64;
typedef unsigned int u32;

// packed ascending key: (float bits of nonneg key) << 32 | idx
// lexicographic u64 compare == (value asc, index asc) == jax top_k tie rule
__device__ __forceinline__ u64 pack_asc(float key, u32 idx) {
  return (((u64)__float_as_uint(key)) << 32) | (u64)idx;
}

// EXACT reference squared distance: ((dx^2+dy^2)+dz^2)+dw^2, no contraction.
// ref d = sqrtf(this).
__device__ __forceinline__ float dist2_ref(const float4 g, const float4 p) {
#pragma clang fp contract(off)
  float dx = g.x - p.x;
  float dy = g.y - p.y;
  float dz = g.z - p.z;
  float dw = g.w - p.w;
  float s = dx * dx + dy * dy;
  s = s + dz * dz;
  s = s + dw * dw;
  return s;
}

// FAST approx squared distance for the threshold pass (contraction allowed).
__device__ __forceinline__ float dist2_fast(const float4 g, const float4 p) {
  float dx = g.x - p.x;
  float dy = g.y - p.y;
  float dz = g.z - p.z;
  float dw = g.w - p.w;
  return fmaf(dx, dx, fmaf(dy, dy, fmaf(dz, dz, dw * dw)));
}

// IoU exactly as reference (cxcywh -> xyxy, clip, same op order)
__device__ __forceinline__ float iou_ref(const float4 g, const float4 p) {
#pragma clang fp contract(off)
  float gx1 = g.x - 0.5f * g.z, gy1 = g.y - 0.5f * g.w;
  float gx2 = g.x + 0.5f * g.z, gy2 = g.y + 0.5f * g.w;
  float px1 = p.x - 0.5f * p.z, py1 = p.y - 0.5f * p.w;
  float px2 = p.x + 0.5f * p.z, py2 = p.y + 0.5f * p.w;
  float ltx = fmaxf(gx1, px1), lty = fmaxf(gy1, py1);
  float rbx = fminf(gx2, px2), rby = fminf(gy2, py2);
  float wx = fmaxf(rbx - ltx, 0.0f), wy = fmaxf(rby - lty, 0.0f);
  float inter = wx * wy;
  float aa = (gx2 - gx1) * (gy2 - gy1);
  float ab = (px2 - px1) * (py2 - py1);
  return inter / ((aa + ab) - inter);
}

// full ascending bitonic sort across one 64-lane wave, u64 keys
__device__ __forceinline__ u64 bitonic64(u64 v, int lane) {
#pragma unroll
  for (int k = 2; k <= 64; k <<= 1) {
#pragma unroll
    for (int j = k >> 1; j > 0; j >>= 1) {
      u64 o = __shfl_xor(v, j, 64);
      bool up = ((lane & k) == 0);
      bool lower = ((lane & j) == 0);
      v = (lower == up) ? (v < o ? v : o) : (v > o ? v : o);
    }
  }
  return v;
}

// full ascending bitonic sort across one 64-lane wave, u32 keys (cheap shfl)
__device__ __forceinline__ u32 bitonic32u(u32 v, int lane) {
#pragma unroll
  for (int k = 2; k <= 64; k <<= 1) {
#pragma unroll
    for (int j = k >> 1; j > 0; j >>= 1) {
      u32 o = (u32)__shfl_xor((int)v, j, 64);
      bool up = ((lane & k) == 0);
      bool lower = ((lane & j) == 0);
      v = (lower == up) ? (v < o ? v : o) : (v > o ? v : o);
    }
  }
  return v;
}

__global__ __launch_bounds__(256) void atss_kernel(
    const float4* __restrict__ pred, const float4* __restrict__ gtb,
    int* __restrict__ out) {
  __shared__ float smin[256];
  __shared__ float ckey[CAP];
  __shared__ unsigned short cidx[CAP];
  __shared__ int kidx[KK];
  __shared__ int nCand;
  __shared__ float sU2;

  const int t = threadIdx.x;
  const int g = blockIdx.x;
  const int b = blockIdx.y;
  if (t == 0) nCand = 0;

  const float4 gt = gtb[b * GG + g];
  const float4* pb = pred + (size_t)b * QQ;

  // ---- pass 1: per-thread float min of approx squared distance ----
  // No index, no sqrt, contraction on: ~9 VALU/element. Two accumulators
  // for ILP.
  float m0 = __uint_as_float(0x7F800000u);  // +inf
  float m1 = m0;
#pragma unroll 8
  for (int j = 0; j < QQ / 512; ++j) {
    int i = t + j * 512;
    float d0 = dist2_fast(gt, pb[i]);
    float d1 = dist2_fast(gt, pb[i + 256]);
    m0 = fminf(m0, d0);
    m1 = fminf(m1, d1);
  }
  float lmin = fminf(m0, m1);
  smin[t] = lmin;
  __syncthreads();

  // ---- threshold U2 = 32nd smallest of 64 lane-merged thread-mins ----
  // >=32 distinct elements have approx d2 <= U2; inflate by 2e-5 rel to
  // cover contraction error (few ulp) and sqrt-collapse ties, so the
  // candidate set {exact d2 <= U2p} is a superset of the reference top-32
  // (including its tie behavior).
  if (t < 64) {
    float a = fminf(fminf(smin[t], smin[t + 64]),
                    fminf(smin[t + 128], smin[t + 192]));
    u32 srt = bitonic32u(__float_as_uint(a), t);  // nonneg floats: bit order
    if (t == 31) sU2 = __uint_as_float(srt) * 1.00002f + 1e-35f;
  }
  __syncthreads();

  // ---- pass 2: collect candidates with exact ref d2 <= U2p ----
  // threads whose own approx min is > U2p cannot contribute: skip rescan
  const float U2p = sU2;
  if (lmin <= U2p) {
    for (int j = 0; j < QQ / 256; ++j) {
      int i = t + j * 256;
      float d2 = dist2_ref(gt, pb[i]);
      if (d2 <= U2p) {
        int pos = atomicAdd(&nCand, 1);
        if (pos < CAP) {
          ckey[pos] = d2;
          cidx[pos] = (unsigned short)i;
        }
      }
    }
  }
  __syncthreads();

  const int n = nCand;  // guaranteed >= 32

  if (n <= CAP) {
    // convert candidate keys to the exact reference distance: d = sqrtf(d2).
    // IEEE sqrtf (no fast-math here) == jnp.sqrt bitwise.
    for (int s = t; s < n; s += 256) ckey[s] = sqrtf(ckey[s]);
  }
  __syncthreads();

  // ---- select top-32 by (d, idx) ascending -> kidx sorted like ref kidx ----
  if (n > CAP) {
    // pathological-only exact serial fallback
    if (t == 0) {
      u64 best[KK];
      for (int l = 0; l < KK; ++l) best[l] = ~0ull;
      for (int i = 0; i < QQ; ++i) {
        float d = sqrtf(dist2_ref(gt, pb[i]));
        u64 pk = pack_asc(d, (u32)i);
        if (pk < best[KK - 1]) {
          int pos = KK - 1;
          while (pos > 0 && best[pos - 1] > pk) {
            best[pos] = best[pos - 1];
            --pos;
          }
          best[pos] = pk;
        }
      }
      for (int l = 0; l < KK; ++l) kidx[l] = (int)(best[l] & 0xFFFFFFFFull);
    }
  } else if (t < 64) {
    if (n <= 64) {
      // fast path (expected ~95%+): one wave bitonic sort
      u64 v = (t < n) ? pack_asc(ckey[t], (u32)cidx[t]) : ~0ull;
      u64 srt = bitonic64(v, t);
      if (t < KK) kidx[t] = (int)(srt & 0xFFFFFFFFull);
    } else {
      // 64 < n <= CAP: 32 rounds of wave-wide argmin extraction
      volatile float* vk = ckey;
      for (int sel = 0; sel < KK; ++sel) {
        u64 lm = ~0ull;
        int ls = -1;
        for (int s = t; s < n; s += 64) {
          float d = vk[s];
          u64 pk = pack_asc(d, (u32)cidx[s]);
          if (pk < lm) {
            lm = pk;
            ls = s;
          }
        }
        u64 w = lm;
#pragma unroll
        for (int j = 32; j > 0; j >>= 1) {
          u64 o = __shfl_xor(w, j, 64);
          w = o < w ? o : w;
        }
        if (lm == w && ls >= 0) {  // unique winner (idx unique)
          vk[ls] = __uint_as_float(0x7F800000u);  // mark used with +inf
          kidx[sel] = (int)(w & 0xFFFFFFFFull);
        }
      }
    }
  }
  __syncthreads();

  // ---- IoU of the 32 candidates, top-9 by (iou desc, position asc) ----
  if (t < 64) {
    u64 v = ~0ull;
    if (t < KK) {
      float iou = iou_ref(gt, pb[kidx[t]]);
      // ~bits(iou) is strictly decreasing in iou (iou >= 0): ascending sort
      // of packed == descending iou, ties -> lower K-position first
      v = (((u64)(~__float_as_uint(iou))) << 32) | (u64)t;
    }
    u64 srt = bitonic64(v, t);
    if (t < NN) {
      int pos = (int)(srt & 0xFFFFFFFFull);
      int base = (b * GG + g) * NN + t;
      out[base] = kidx[pos];                // pred_idx
      out[BB * GG * NN + base] = g;         // gt_idx
    }
  }
}

extern "C" void kernel_launch(void* const* d_in, const int* in_sizes, int n_in,
                              void* d_out, int out_size, void* d_ws, size_t ws_size,
                              hipStream_t stream) {
  (void)in_sizes;
  (void)n_in;
  (void)out_size;
  (void)d_ws;
  (void)ws_size;
  const float4* pred = (const float4*)d_in[0];  // [B, Q, 4] f32
  const float4* gt = (const float4*)d_in[1];    // [B, G, 4] f32
  int* out = (int*)d_out;                       // [2 * B * G * N] int32
  dim3 grid(GG, BB);
  atss_kernel<<<grid, 256, 0, stream>>>(pred, gt, out);
}

// Round 3
// 114.068 us; speedup vs baseline: 1.4457x; 1.1897x over previous
//
#include <hip/hip_runtime.h>

#define BB 32
#define QQ 16384
#define GG 128
#define KK 32
#define NN 9
#define TT 8     // GTs per block (one per wave in the tail)
#define TH 512   // threads per block = 8 waves
#define CAP 256  // per-GT candidate capacity

typedef unsigned long long u64;
typedef unsigned int u32;

#define INFF __uint_as_float(0x7F800000u)

// packed ascending key: (float bits of nonneg key) << 32 | idx
// lexicographic u64 compare == (value asc, index asc) == jax top_k tie rule
__device__ __forceinline__ u64 pack_asc(float key, u32 idx) {
  return (((u64)__float_as_uint(key)) << 32) | (u64)idx;
}

// EXACT reference squared distance: ((dx^2+dy^2)+dz^2)+dw^2, no contraction.
// ref d = sqrtf(this).
__device__ __forceinline__ float dist2_ref(const float4 g, const float4 p) {
#pragma clang fp contract(off)
  float dx = g.x - p.x;
  float dy = g.y - p.y;
  float dz = g.z - p.z;
  float dw = g.w - p.w;
  float s = dx * dx + dy * dy;
  s = s + dz * dz;
  s = s + dw * dw;
  return s;
}

// FAST approx squared distance for the threshold pass (contraction allowed).
__device__ __forceinline__ float dist2_fast(const float4 g, const float4 p) {
  float dx = g.x - p.x;
  float dy = g.y - p.y;
  float dz = g.z - p.z;
  float dw = g.w - p.w;
  return fmaf(dx, dx, fmaf(dy, dy, fmaf(dz, dz, dw * dw)));
}

// IoU exactly as reference (cxcywh -> xyxy, clip, same op order)
__device__ __forceinline__ float iou_ref(const float4 g, const float4 p) {
#pragma clang fp contract(off)
  float gx1 = g.x - 0.5f * g.z, gy1 = g.y - 0.5f * g.w;
  float gx2 = g.x + 0.5f * g.z, gy2 = g.y + 0.5f * g.w;
  float px1 = p.x - 0.5f * p.z, py1 = p.y - 0.5f * p.w;
  float px2 = p.x + 0.5f * p.z, py2 = p.y + 0.5f * p.w;
  float ltx = fmaxf(gx1, px1), lty = fmaxf(gy1, py1);
  float rbx = fminf(gx2, px2), rby = fminf(gy2, py2);
  float wx = fmaxf(rbx - ltx, 0.0f), wy = fmaxf(rby - lty, 0.0f);
  float inter = wx * wy;
  float aa = (gx2 - gx1) * (gy2 - gy1);
  float ab = (px2 - px1) * (py2 - py1);
  return inter / ((aa + ab) - inter);
}

// full ascending bitonic sort across one 64-lane wave, u64 keys
__device__ __forceinline__ u64 bitonic64(u64 v, int lane) {
#pragma unroll
  for (int k = 2; k <= 64; k <<= 1) {
#pragma unroll
    for (int j = k >> 1; j > 0; j >>= 1) {
      u64 o = __shfl_xor(v, j, 64);
      bool up = ((lane & k) == 0);
      bool lower = ((lane & j) == 0);
      v = (lower == up) ? (v < o ? v : o) : (v > o ? v : o);
    }
  }
  return v;
}

// full ascending bitonic sort across one 64-lane wave, u32 keys (cheap shfl)
__device__ __forceinline__ u32 bitonic32u(u32 v, int lane) {
#pragma unroll
  for (int k = 2; k <= 64; k <<= 1) {
#pragma unroll
    for (int j = k >> 1; j > 0; j >>= 1) {
      u32 o = (u32)__shfl_xor((int)v, j, 64);
      bool up = ((lane & k) == 0);
      bool lower = ((lane & j) == 0);
      v = (lower == up) ? (v < o ? v : o) : (v > o ? v : o);
    }
  }
  return v;
}

__global__ __launch_bounds__(TH) void atss_kernel(
    const float4* __restrict__ pred, const float4* __restrict__ gtb,
    int* __restrict__ out) {
  __shared__ float smin[TT * TH];          // 16 KB
  __shared__ float ckey[TT][CAP];          // 8 KB
  __shared__ unsigned short cidx[TT][CAP]; // 4 KB
  __shared__ int kidx[TT][KK];             // 1 KB
  __shared__ int nC[TT];
  __shared__ float sU2[TT];

  const int t = threadIdx.x;
  const int g0 = blockIdx.x * TT;
  const int b = blockIdx.y;
  if (t < TT) nC[t] = 0;

  // 8 GT boxes, block-uniform addresses -> scalar loads / SGPRs
  float4 G[TT];
#pragma unroll
  for (int gg = 0; gg < TT; ++gg) G[gg] = gtb[b * GG + g0 + gg];

  const float4* pb = pred + (size_t)b * QQ;

  // ---- pass 1: per-thread approx-d2 min for all 8 GTs ----
  // 1 float4 load feeds 8x(4 sub + 3 fma + 1 mul + 1 min) = 72 VALU.
  float mn[TT];
#pragma unroll
  for (int gg = 0; gg < TT; ++gg) mn[gg] = INFF;
#pragma unroll 4
  for (int j = 0; j < QQ / TH; ++j) {
    float4 p = pb[t + j * TH];
#pragma unroll
    for (int gg = 0; gg < TT; ++gg) {
      mn[gg] = fminf(mn[gg], dist2_fast(G[gg], p));
    }
  }
#pragma unroll
  for (int gg = 0; gg < TT; ++gg) smin[gg * TH + t] = mn[gg];
  __syncthreads();

  const int w = t >> 6;    // wave id = GT slot in the tail
  const int lane = t & 63;

  // ---- threshold per GT: wave w merges 512 thread-mins -> 64 lane-mins,
  // sorts, takes the 32nd smallest. Each lane-min covers 256 disjoint
  // elements, so >=32 elements have approx d2 <= U. Inflate to cover
  // contraction error and sqrt-collapse ties.
  {
    float a = INFF;
#pragma unroll
    for (int k = 0; k < TH / 64; ++k)
      a = fminf(a, smin[w * TH + lane + k * 64]);
    u32 srt = bitonic32u(__float_as_uint(a), lane);  // nonneg: bit order
    if (lane == 31) sU2[w] = __uint_as_float(srt) * 1.00002f + 1e-35f;
  }
  __syncthreads();

  // ---- pass 2: collect exact-d2 candidates per GT ----
  float U2[TT];
  int mask = 0;
#pragma unroll
  for (int gg = 0; gg < TT; ++gg) {
    U2[gg] = sU2[gg];
    if (mn[gg] <= U2[gg]) mask |= 1 << gg;
  }
  if (mask) {
    for (int j = 0; j < QQ / TH; ++j) {
      int i = t + j * TH;
      float4 p = pb[i];
#pragma unroll
      for (int gg = 0; gg < TT; ++gg) {
        if (!(mask & (1 << gg))) continue;
        float d2 = dist2_ref(G[gg], p);
        if (d2 <= U2[gg]) {
          int pos = atomicAdd(&nC[gg], 1);
          if (pos < CAP) {
            ckey[gg][pos] = d2;
            cidx[gg][pos] = (unsigned short)i;
          }
        }
      }
    }
  }
  __syncthreads();

  const int n = nC[w];  // guaranteed >= 32
  const float4 gt = gtb[b * GG + g0 + w];  // per-wave reload (non-uniform idx)

  // ---- convert candidate keys to exact reference distance ----
  if (n <= CAP) {
    for (int s = lane; s < n; s += 64) ckey[w][s] = sqrtf(ckey[w][s]);
  }
  __syncthreads();  // uniform barrier: makes in-wave LDS writes visible

  // ---- select top-32 by (d, idx) ascending ----
  if (n > CAP) {
    // pathological-only exact serial fallback (never on continuous data)
    if (lane == 0) {
      u64 best[KK];
      for (int l = 0; l < KK; ++l) best[l] = ~0ull;
      for (int i = 0; i < QQ; ++i) {
        float d = sqrtf(dist2_ref(gt, pb[i]));
        u64 pk = pack_asc(d, (u32)i);
        if (pk < best[KK - 1]) {
          int pos = KK - 1;
          while (pos > 0 && best[pos - 1] > pk) {
            best[pos] = best[pos - 1];
            --pos;
          }
          best[pos] = pk;
        }
      }
      for (int l = 0; l < KK; ++l) kidx[w][l] = (int)(best[l] & 0xFFFFFFFFull);
    }
  } else if (n <= 64) {
    // fast path (expected ~99%): one wave bitonic sort
    u64 v = (lane < n) ? pack_asc(ckey[w][lane], (u32)cidx[w][lane]) : ~0ull;
    u64 srt = bitonic64(v, lane);
    if (lane < KK) kidx[w][lane] = (int)(srt & 0xFFFFFFFFull);
  } else {
    // 64 < n <= CAP: 32 rounds of wave-wide argmin extraction
    volatile float* vk = ckey[w];
    for (int sel = 0; sel < KK; ++sel) {
      u64 lm = ~0ull;
      int ls = -1;
      for (int s = lane; s < n; s += 64) {
        float d = vk[s];
        u64 pk = pack_asc(d, (u32)cidx[w][s]);
        if (pk < lm) {
          lm = pk;
          ls = s;
        }
      }
      u64 ww = lm;
#pragma unroll
      for (int j = 32; j > 0; j >>= 1) {
        u64 o = __shfl_xor(ww, j, 64);
        ww = o < ww ? o : ww;
      }
      if (lm == ww && ls >= 0) {  // unique winner (idx unique)
        vk[ls] = INFF;            // mark used
        kidx[w][sel] = (int)(ww & 0xFFFFFFFFull);
      }
    }
  }
  __syncthreads();  // uniform barrier before IoU reads kidx

  // ---- IoU of the 32 candidates, top-9 by (iou desc, position asc) ----
  {
    u64 v = ~0ull;
    if (lane < KK) {
      float iou = iou_ref(gt, pb[kidx[w][lane]]);
      // ~bits(iou) strictly decreasing in iou (iou >= 0): ascending packed
      // sort == descending iou, ties -> lower K-position first
      v = (((u64)(~__float_as_uint(iou))) << 32) | (u64)lane;
    }
    u64 srt = bitonic64(v, lane);
    if (lane < NN) {
      int pos = (int)(srt & 0xFFFFFFFFull);
      int base = (b * GG + g0 + w) * NN + lane;
      out[base] = kidx[w][pos];      // pred_idx
      out[BB * GG * NN + base] = g0 + w;  // gt_idx
    }
  }
}

extern "C" void kernel_launch(void* const* d_in, const int* in_sizes, int n_in,
                              void* d_out, int out_size, void* d_ws, size_t ws_size,
                              hipStream_t stream) {
  (void)in_sizes;
  (void)n_in;
  (void)out_size;
  (void)d_ws;
  (void)ws_size;
  const float4* pred = (const float4*)d_in[0];  // [B, Q, 4] f32
  const float4* gt = (const float4*)d_in[1];    // [B, G, 4] f32
  int* out = (int*)d_out;                       // [2 * B * G * N] int32
  dim3 grid(GG / TT, BB);
  atss_kernel<<<grid, TH, 0, stream>>>(pred, gt, out);
}

// Round 4
// 104.084 us; speedup vs baseline: 1.5844x; 1.0959x over previous
//
#include <hip/hip_runtime.h>

#define BB 32
#define QQ 16384
#define GG 128
#define KK 32
#define NN 9
#define TT 8      // GTs per block
#define TH 1024   // threads per block = 16 waves (grid 512 -> 8192 waves = 100% occ)
#define CAP 256   // per-GT candidate capacity
#define WCAP 2048 // worklist capacity (expected ~400)

typedef unsigned long long u64;
typedef unsigned int u32;

#define INFF __uint_as_float(0x7F800000u)

// packed ascending key: (float bits of nonneg key) << 32 | idx
// lexicographic u64 compare == (value asc, index asc) == jax top_k tie rule
__device__ __forceinline__ u64 pack_asc(float key, u32 idx) {
  return (((u64)__float_as_uint(key)) << 32) | (u64)idx;
}

// EXACT reference squared distance: ((dx^2+dy^2)+dz^2)+dw^2, no contraction.
// ref d = sqrtf(this).
__device__ __forceinline__ float dist2_ref(const float4 g, const float4 p) {
#pragma clang fp contract(off)
  float dx = g.x - p.x;
  float dy = g.y - p.y;
  float dz = g.z - p.z;
  float dw = g.w - p.w;
  float s = dx * dx + dy * dy;
  s = s + dz * dz;
  s = s + dw * dw;
  return s;
}

// FAST approx squared distance for the threshold pass (contraction allowed).
__device__ __forceinline__ float dist2_fast(const float4 g, const float4 p) {
  float dx = g.x - p.x;
  float dy = g.y - p.y;
  float dz = g.z - p.z;
  float dw = g.w - p.w;
  return fmaf(dx, dx, fmaf(dy, dy, fmaf(dz, dz, dw * dw)));
}

// IoU exactly as reference (cxcywh -> xyxy, clip, same op order)
__device__ __forceinline__ float iou_ref(const float4 g, const float4 p) {
#pragma clang fp contract(off)
  float gx1 = g.x - 0.5f * g.z, gy1 = g.y - 0.5f * g.w;
  float gx2 = g.x + 0.5f * g.z, gy2 = g.y + 0.5f * g.w;
  float px1 = p.x - 0.5f * p.z, py1 = p.y - 0.5f * p.w;
  float px2 = p.x + 0.5f * p.z, py2 = p.y + 0.5f * p.w;
  float ltx = fmaxf(gx1, px1), lty = fmaxf(gy1, py1);
  float rbx = fminf(gx2, px2), rby = fminf(gy2, py2);
  float wx = fmaxf(rbx - ltx, 0.0f), wy = fmaxf(rby - lty, 0.0f);
  float inter = wx * wy;
  float aa = (gx2 - gx1) * (gy2 - gy1);
  float ab = (px2 - px1) * (py2 - py1);
  return inter / ((aa + ab) - inter);
}

// full ascending bitonic sort across one 64-lane wave, u64 keys
__device__ __forceinline__ u64 bitonic64(u64 v, int lane) {
#pragma unroll
  for (int k = 2; k <= 64; k <<= 1) {
#pragma unroll
    for (int j = k >> 1; j > 0; j >>= 1) {
      u64 o = __shfl_xor(v, j, 64);
      bool up = ((lane & k) == 0);
      bool lower = ((lane & j) == 0);
      v = (lower == up) ? (v < o ? v : o) : (v > o ? v : o);
    }
  }
  return v;
}

// full ascending bitonic sort across one 64-lane wave, u32 keys (cheap shfl)
__device__ __forceinline__ u32 bitonic32u(u32 v, int lane) {
#pragma unroll
  for (int k = 2; k <= 64; k <<= 1) {
#pragma unroll
    for (int j = k >> 1; j > 0; j >>= 1) {
      u32 o = (u32)__shfl_xor((int)v, j, 64);
      bool up = ((lane & k) == 0);
      bool lower = ((lane & j) == 0);
      v = (lower == up) ? (v < o ? v : o) : (v > o ? v : o);
    }
  }
  return v;
}

__global__ __launch_bounds__(TH) void atss_kernel(
    const float4* __restrict__ pred, const float4* __restrict__ gtb,
    int* __restrict__ out) {
  __shared__ float smin[TT * TH];                      // 32 KB
  __shared__ __align__(16) float sG[TT][4];            // gt boxes (dyn index)
  __shared__ float ckey[TT][CAP];                      // 8 KB
  __shared__ unsigned short cidx[TT][CAP];             // 4 KB
  __shared__ unsigned short wl[WCAP];                  // 4 KB
  __shared__ int kidx[TT][KK];                         // 1 KB
  __shared__ int nC[TT];
  __shared__ int nW;
  __shared__ float sU2[TT];

  const int t = threadIdx.x;
  const int g0 = blockIdx.x * TT;
  const int b = blockIdx.y;
  if (t < TT) {
    nC[t] = 0;
    float4 gv = gtb[b * GG + g0 + t];
    sG[t][0] = gv.x; sG[t][1] = gv.y; sG[t][2] = gv.z; sG[t][3] = gv.w;
  }
  if (t == TT) nW = 0;

  // 8 GT boxes from block-uniform addresses -> scalar loads / SGPRs
  float4 G[TT];
#pragma unroll
  for (int gg = 0; gg < TT; ++gg) G[gg] = gtb[b * GG + g0 + gg];

  const float4* pb = pred + (size_t)b * QQ;

  // ---- pass 1: per-thread approx-d2 min for all 8 GTs ----
  // 1 float4 load feeds 8x(4 sub + 3 fma + 1 mul + 1 min) = 72 VALU.
  float mn[TT];
#pragma unroll
  for (int gg = 0; gg < TT; ++gg) mn[gg] = INFF;
#pragma unroll 4
  for (int j = 0; j < QQ / TH; ++j) {
    float4 p = pb[t + j * TH];
#pragma unroll
    for (int gg = 0; gg < TT; ++gg) {
      mn[gg] = fminf(mn[gg], dist2_fast(G[gg], p));
    }
  }
#pragma unroll
  for (int gg = 0; gg < TT; ++gg) smin[gg * TH + t] = mn[gg];
  __syncthreads();

  const int w = t >> 6;    // wave id; waves 0..TT-1 own one GT each in tail
  const int lane = t & 63;

  // ---- threshold per GT: wave w merges TH thread-mins -> 64 lane-mins,
  // sorts, takes the 32nd smallest U. Each lane-min covers QQ/64 disjoint
  // elements, so >=32 distinct elements have approx d2 <= U. Inflate to
  // cover contraction error (few ulp) and sqrt-collapse ties.
  if (w < TT) {
    float a = INFF;
#pragma unroll
    for (int k = 0; k < TH / 64; ++k)
      a = fminf(a, smin[w * TH + lane + k * 64]);
    u32 srt = bitonic32u(__float_as_uint(a), lane);  // nonneg: bit order
    if (lane == 31) sU2[w] = __uint_as_float(srt) * 1.00002f + 1e-35f;
  }
  __syncthreads();

  // ---- build compacted worklist of active (thread-range, gt) pairs ----
  // Any element of the reference top-32 (incl. ties) has approx d2 < U2p,
  // so its range-owner thread satisfies mn[gg] <= U2p and pushes an item.
#pragma unroll
  for (int gg = 0; gg < TT; ++gg) {
    if (mn[gg] <= sU2[gg]) {
      int pos = atomicAdd(&nW, 1);
      if (pos < WCAP) wl[pos] = (unsigned short)((t << 3) | gg);
    }
  }
  __syncthreads();

  const int nWf = nW;
  if (nWf <= WCAP) {
    // ---- pass 2 (compacted): drain worklist, exact-d2 collection ----
    for (int it = t; it < nWf; it += TH) {
      int e = wl[it];
      int tt = e >> 3, gg = e & 7;
      float4 gv = *(const float4*)sG[gg];
      float U2p = sU2[gg];
      for (int j = 0; j < QQ / TH; ++j) {
        int i = tt + j * TH;
        float d2 = dist2_ref(gv, pb[i]);
        if (d2 <= U2p) {
          int pos = atomicAdd(&nC[gg], 1);
          if (pos < CAP) {
            ckey[gg][pos] = d2;
            cidx[gg][pos] = (unsigned short)i;
          }
        }
      }
    }
  } else {
    // ---- pathological fallback: dense masked rescan (block-uniform) ----
    int mask = 0;
#pragma unroll
    for (int gg = 0; gg < TT; ++gg)
      if (mn[gg] <= sU2[gg]) mask |= 1 << gg;
    if (mask) {
      for (int j = 0; j < QQ / TH; ++j) {
        int i = t + j * TH;
        float4 p = pb[i];
#pragma unroll
        for (int gg = 0; gg < TT; ++gg) {
          if (!(mask & (1 << gg))) continue;
          float d2 = dist2_ref(G[gg], p);
          if (d2 <= sU2[gg]) {
            int pos = atomicAdd(&nC[gg], 1);
            if (pos < CAP) {
              ckey[gg][pos] = d2;
              cidx[gg][pos] = (unsigned short)i;
            }
          }
        }
      }
    }
  }
  __syncthreads();

  const int n = (w < TT) ? nC[w] : 0;  // per-GT count, >= 32 guaranteed
  float4 gt;
  if (w < TT) gt = gtb[b * GG + g0 + w];

  // ---- convert candidate keys to exact reference distance ----
  // IEEE sqrtf (no fast-math) == jnp.sqrt bitwise.
  if (w < TT && n <= CAP) {
    for (int s = lane; s < n; s += 64) ckey[w][s] = sqrtf(ckey[w][s]);
  }
  __syncthreads();

  // ---- select top-32 by (d, idx) ascending -> kidx like ref ----
  if (w < TT) {
    if (n > CAP) {
      // pathological-only exact serial fallback
      if (lane == 0) {
        u64 best[KK];
        for (int l = 0; l < KK; ++l) best[l] = ~0ull;
        for (int i = 0; i < QQ; ++i) {
          float d = sqrtf(dist2_ref(gt, pb[i]));
          u64 pk = pack_asc(d, (u32)i);
          if (pk < best[KK - 1]) {
            int pos = KK - 1;
            while (pos > 0 && best[pos - 1] > pk) {
              best[pos] = best[pos - 1];
              --pos;
            }
            best[pos] = pk;
          }
        }
        for (int l = 0; l < KK; ++l)
          kidx[w][l] = (int)(best[l] & 0xFFFFFFFFull);
      }
    } else if (n <= 64) {
      // fast path (expected ~99%): one wave bitonic sort
      u64 v = (lane < n) ? pack_asc(ckey[w][lane], (u32)cidx[w][lane]) : ~0ull;
      u64 srt = bitonic64(v, lane);
      if (lane < KK) kidx[w][lane] = (int)(srt & 0xFFFFFFFFull);
    } else {
      // 64 < n <= CAP: 32 rounds of wave-wide argmin extraction
      volatile float* vk = ckey[w];
      for (int sel = 0; sel < KK; ++sel) {
        u64 lm = ~0ull;
        int ls = -1;
        for (int s = lane; s < n; s += 64) {
          float d = vk[s];
          u64 pk = pack_asc(d, (u32)cidx[w][s]);
          if (pk < lm) {
            lm = pk;
            ls = s;
          }
        }
        u64 ww = lm;
#pragma unroll
        for (int j = 32; j > 0; j >>= 1) {
          u64 o = __shfl_xor(ww, j, 64);
          ww = o < ww ? o : ww;
        }
        if (lm == ww && ls >= 0) {  // unique winner (idx unique)
          vk[ls] = INFF;            // mark used
          kidx[w][sel] = (int)(ww & 0xFFFFFFFFull);
        }
      }
    }
  }
  __syncthreads();

  // ---- IoU of the 32 candidates, top-9 by (iou desc, position asc) ----
  if (w < TT) {
    u64 v = ~0ull;
    if (lane < KK) {
      float iou = iou_ref(gt, pb[kidx[w][lane]]);
      // ~bits(iou) strictly decreasing in iou (iou >= 0): ascending packed
      // sort == descending iou, ties -> lower K-position first
      v = (((u64)(~__float_as_uint(iou))) << 32) | (u64)lane;
    }
    u64 srt = bitonic64(v, lane);
    if (lane < NN) {
      int pos = (int)(srt & 0xFFFFFFFFull);
      int base = (b * GG + g0 + w) * NN + lane;
      out[base] = kidx[w][pos];           // pred_idx
      out[BB * GG * NN + base] = g0 + w;  // gt_idx
    }
  }
}

extern "C" void kernel_launch(void* const* d_in, const int* in_sizes, int n_in,
                              void* d_out, int out_size, void* d_ws, size_t ws_size,
                              hipStream_t stream) {
  (void)in_sizes;
  (void)n_in;
  (void)out_size;
  (void)d_ws;
  (void)ws_size;
  const float4* pred = (const float4*)d_in[0];  // [B, Q, 4] f32
  const float4* gt = (const float4*)d_in[1];    // [B, G, 4] f32
  int* out = (int*)d_out;                       // [2 * B * G * N] int32
  dim3 grid(GG / TT, BB);
  atss_kernel<<<grid, TH, 0, stream>>>(pred, gt, out);
}

// Round 5
// 95.187 us; speedup vs baseline: 1.7324x; 1.0935x over previous
//
#include <hip/hip_runtime.h>

#define BB 32
#define QQ 16384
#define GG 128
#define KK 32
#define NN 9
#define TT 8      // GTs per block
#define TH 1024   // threads per block = 16 waves
#define CAP 256   // per-GT candidate capacity
#define WCAP 2048 // worklist capacity (expected ~350)

typedef unsigned long long u64;
typedef unsigned int u32;

#define INFF __uint_as_float(0x7F800000u)

// packed ascending key: (float bits of nonneg key) << 32 | idx
// lexicographic u64 compare == (value asc, index asc) == jax top_k tie rule
__device__ __forceinline__ u64 pack_asc(float key, u32 idx) {
  return (((u64)__float_as_uint(key)) << 32) | (u64)idx;
}

// EXACT reference squared distance: ((dx^2+dy^2)+dz^2)+dw^2, no contraction.
// ref d = sqrtf(this).
__device__ __forceinline__ float dist2_ref(const float4 g, const float4 p) {
#pragma clang fp contract(off)
  float dx = g.x - p.x;
  float dy = g.y - p.y;
  float dz = g.z - p.z;
  float dw = g.w - p.w;
  float s = dx * dx + dy * dy;
  s = s + dz * dz;
  s = s + dw * dw;
  return s;
}

// IoU exactly as reference (cxcywh -> xyxy, clip, same op order)
__device__ __forceinline__ float iou_ref(const float4 g, const float4 p) {
#pragma clang fp contract(off)
  float gx1 = g.x - 0.5f * g.z, gy1 = g.y - 0.5f * g.w;
  float gx2 = g.x + 0.5f * g.z, gy2 = g.y + 0.5f * g.w;
  float px1 = p.x - 0.5f * p.z, py1 = p.y - 0.5f * p.w;
  float px2 = p.x + 0.5f * p.z, py2 = p.y + 0.5f * p.w;
  float ltx = fmaxf(gx1, px1), lty = fmaxf(gy1, py1);
  float rbx = fminf(gx2, px2), rby = fminf(gy2, py2);
  float wx = fmaxf(rbx - ltx, 0.0f), wy = fmaxf(rby - lty, 0.0f);
  float inter = wx * wy;
  float aa = (gx2 - gx1) * (gy2 - gy1);
  float ab = (px2 - px1) * (py2 - py1);
  return inter / ((aa + ab) - inter);
}

// full ascending bitonic sort across one 64-lane wave, u64 keys
__device__ __forceinline__ u64 bitonic64(u64 v, int lane) {
#pragma unroll
  for (int k = 2; k <= 64; k <<= 1) {
#pragma unroll
    for (int j = k >> 1; j > 0; j >>= 1) {
      u64 o = __shfl_xor(v, j, 64);
      bool up = ((lane & k) == 0);
      bool lower = ((lane & j) == 0);
      v = (lower == up) ? (v < o ? v : o) : (v > o ? v : o);
    }
  }
  return v;
}

// full ascending bitonic sort across one 64-lane wave, float keys
// (handles negatives; values are finite or +inf padding, never NaN)
__device__ __forceinline__ float bitonic64f(float v, int lane) {
#pragma unroll
  for (int k = 2; k <= 64; k <<= 1) {
#pragma unroll
    for (int j = k >> 1; j > 0; j >>= 1) {
      float o = __shfl_xor(v, j, 64);
      bool up = ((lane & k) == 0);
      bool lower = ((lane & j) == 0);
      v = (lower == up) ? fminf(v, o) : fmaxf(v, o);
    }
  }
  return v;
}

__global__ __launch_bounds__(TH, 8) void atss_kernel(
    const float4* __restrict__ pred, const float4* __restrict__ gtb,
    int* __restrict__ out) {
  __shared__ float smin[TT * TH];                      // 32 KB
  __shared__ __align__(16) float sG[TT][4];            // gt boxes (dyn index)
  __shared__ float ckey[TT][CAP];                      // 8 KB
  __shared__ unsigned short cidx[TT][CAP];             // 4 KB
  __shared__ unsigned short wl[WCAP];                  // 4 KB
  __shared__ int kidx[TT][KK];                         // 1 KB
  __shared__ int nC[TT];
  __shared__ int nW;
  __shared__ float sUs[TT];  // inflated s-space threshold (worklist test)
  __shared__ float sT[TT];   // d2-space collection threshold

  const int t = threadIdx.x;
  // XCD-aware swizzle: all 16 g-group blocks of one batch land on one XCD
  // (assuming round-robin flat->XCD; if wrong, only locality changes).
  const int f = blockIdx.x;
  const int b = (f & 7) * 4 + (f >> 7);
  const int g0 = ((f >> 3) & 15) * TT;

  if (t < TT) {
    nC[t] = 0;
    float4 gv = gtb[b * GG + g0 + t];
    sG[t][0] = gv.x; sG[t][1] = gv.y; sG[t][2] = gv.z; sG[t][3] = gv.w;
  }
  if (t == TT) nW = 0;

  // 8 GT boxes from block-uniform addresses -> scalar loads / SGPRs
  float4 G[TT];
#pragma unroll
  for (int gg = 0; gg < TT; ++gg) G[gg] = gtb[b * GG + g0 + gg];

  const float4* pb = pred + (size_t)b * QQ;

  // ---- pass 1: per-thread min of s = |p|^2 - 2 g.p  (d2 shifted by -|g|^2,
  // a per-GT constant -> same argmin/ordering). pp amortized over 8 GTs;
  // per GT: 4 fma/mul + 1 fma + 1 min = 6 VALU. g stays in SGPRs.
  float mn[TT];
#pragma unroll
  for (int gg = 0; gg < TT; ++gg) mn[gg] = INFF;
  float4 p = pb[t];
#pragma unroll
  for (int j = 0; j < QQ / TH; ++j) {
    float4 pn = p;
    if (j + 1 < QQ / TH) pn = pb[t + (j + 1) * TH];  // prefetch next
    float pp = fmaf(p.x, p.x, fmaf(p.y, p.y, fmaf(p.z, p.z, p.w * p.w)));
#pragma unroll
    for (int gg = 0; gg < TT; ++gg) {
      float dot = fmaf(G[gg].x, p.x,
                  fmaf(G[gg].y, p.y,
                  fmaf(G[gg].z, p.z, G[gg].w * p.w)));
      float s = fmaf(-2.0f, dot, pp);
      mn[gg] = fminf(mn[gg], s);
    }
    p = pn;
  }
#pragma unroll
  for (int gg = 0; gg < TT; ++gg) smin[gg * TH + t] = mn[gg];
  __syncthreads();

  const int w = t >> 6;    // wave id; waves 0..TT-1 own one GT each in tail
  const int lane = t & 63;

  // ---- threshold per GT: wave w merges TH thread-mins -> 64 lane-mins,
  // sorts, takes the 32nd smallest U_s. Each lane-min covers QQ/64 disjoint
  // elements, so >=32 distinct elements have approx s <= U_s. Inflation
  // covers fma-form vs ref-form rounding (~5e-7 abs) and sqrt-collapse ties.
  if (w < TT) {
    float a = INFF;
#pragma unroll
    for (int k = 0; k < TH / 64; ++k)
      a = fminf(a, smin[w * TH + lane + k * 64]);
    float srt = bitonic64f(a, lane);
    if (lane == 31) {
      float4 gv = *(const float4*)sG[w];
      float gg2 = fmaf(gv.x, gv.x,
                  fmaf(gv.y, gv.y, fmaf(gv.z, gv.z, gv.w * gv.w)));
      sUs[w] = srt + fabsf(srt) * 2e-5f + 4e-6f;            // s-space, inflated
      sT[w] = fmaxf(srt + gg2, 0.0f) * 1.00002f + 4e-6f;    // d2-space
    }
  }
  __syncthreads();

  // ---- build compacted worklist of active (thread-range, gt) pairs ----
  // Every reference top-32 element (incl. ties) has approx s <= sUs, so its
  // range-owner thread pushes an item.
#pragma unroll
  for (int gg = 0; gg < TT; ++gg) {
    if (mn[gg] <= sUs[gg]) {
      int pos = atomicAdd(&nW, 1);
      if (pos < WCAP) wl[pos] = (unsigned short)((t << 3) | gg);
    }
  }
  __syncthreads();

  const int nWf = nW;
  if (nWf <= WCAP) {
    // ---- pass 2 (compacted): drain worklist, exact-d2 collection ----
    for (int it = t; it < nWf; it += TH) {
      int e = wl[it];
      int tt = e >> 3, gg = e & 7;
      float4 gv = *(const float4*)sG[gg];
      float T = sT[gg];
      for (int j = 0; j < QQ / TH; ++j) {
        int i = tt + j * TH;
        float d2 = dist2_ref(gv, pb[i]);
        if (d2 <= T) {
          int pos = atomicAdd(&nC[gg], 1);
          if (pos < CAP) {
            ckey[gg][pos] = d2;
            cidx[gg][pos] = (unsigned short)i;
          }
        }
      }
    }
  } else {
    // ---- pathological fallback: dense masked rescan (block-uniform) ----
    int mask = 0;
#pragma unroll
    for (int gg = 0; gg < TT; ++gg)
      if (mn[gg] <= sUs[gg]) mask |= 1 << gg;
    if (mask) {
      for (int j = 0; j < QQ / TH; ++j) {
        int i = t + j * TH;
        float4 pv = pb[i];
#pragma unroll
        for (int gg = 0; gg < TT; ++gg) {
          if (!(mask & (1 << gg))) continue;
          float d2 = dist2_ref(G[gg], pv);
          if (d2 <= sT[gg]) {
            int pos = atomicAdd(&nC[gg], 1);
            if (pos < CAP) {
              ckey[gg][pos] = d2;
              cidx[gg][pos] = (unsigned short)i;
            }
          }
        }
      }
    }
  }
  __syncthreads();

  const int n = (w < TT) ? nC[w] : 0;  // per-GT count, >= 32 guaranteed
  float4 gt;
  if (w < TT) gt = *(const float4*)sG[w];

  // ---- select top-32 by (d, idx) ascending; d = sqrtf(d2) on the fly.
  // IEEE sqrtf (no fast-math) == jnp.sqrt bitwise.
  if (w < TT) {
    if (n > CAP) {
      // pathological-only exact serial fallback
      if (lane == 0) {
        u64 best[KK];
        for (int l = 0; l < KK; ++l) best[l] = ~0ull;
        for (int i = 0; i < QQ; ++i) {
          float d = sqrtf(dist2_ref(gt, pb[i]));
          u64 pk = pack_asc(d, (u32)i);
          if (pk < best[KK - 1]) {
            int pos = KK - 1;
            while (pos > 0 && best[pos - 1] > pk) {
              best[pos] = best[pos - 1];
              --pos;
            }
            best[pos] = pk;
          }
        }
        for (int l = 0; l < KK; ++l)
          kidx[w][l] = (int)(best[l] & 0xFFFFFFFFull);
      }
    } else if (n <= 64) {
      // fast path (expected ~99%): one wave bitonic sort
      u64 v = (lane < n) ? pack_asc(sqrtf(ckey[w][lane]), (u32)cidx[w][lane])
                         : ~0ull;
      u64 srt = bitonic64(v, lane);
      if (lane < KK) kidx[w][lane] = (int)(srt & 0xFFFFFFFFull);
    } else {
      // 64 < n <= CAP: 32 rounds of wave-wide argmin extraction
      volatile float* vk = ckey[w];
      for (int sel = 0; sel < KK; ++sel) {
        u64 lm = ~0ull;
        int ls = -1;
        for (int s = lane; s < n; s += 64) {
          float d = sqrtf(vk[s]);  // sqrtf(inf)=inf for consumed slots
          u64 pk = pack_asc(d, (u32)cidx[w][s]);
          if (pk < lm) {
            lm = pk;
            ls = s;
          }
        }
        u64 ww = lm;
#pragma unroll
        for (int j = 32; j > 0; j >>= 1) {
          u64 o = __shfl_xor(ww, j, 64);
          ww = o < ww ? o : ww;
        }
        if (lm == ww && ls >= 0) {  // unique winner (idx unique)
          vk[ls] = INFF;            // mark used
          kidx[w][sel] = (int)(ww & 0xFFFFFFFFull);
        }
      }
    }
  }
  __syncthreads();

  // ---- IoU of the 32 candidates, top-9 by (iou desc, position asc) ----
  if (w < TT) {
    u64 v = ~0ull;
    if (lane < KK) {
      float iou = iou_ref(gt, pb[kidx[w][lane]]);
      // ~bits(iou) strictly decreasing in iou (iou >= 0): ascending packed
      // sort == descending iou, ties -> lower K-position first
      v = (((u64)(~__float_as_uint(iou))) << 32) | (u64)lane;
    }
    u64 srt = bitonic64(v, lane);
    if (lane < NN) {
      int pos = (int)(srt & 0xFFFFFFFFull);
      int base = (b * GG + g0 + w) * NN + lane;
      out[base] = kidx[w][pos];           // pred_idx
      out[BB * GG * NN + base] = g0 + w;  // gt_idx
    }
  }
}

extern "C" void kernel_launch(void* const* d_in, const int* in_sizes, int n_in,
                              void* d_out, int out_size, void* d_ws, size_t ws_size,
                              hipStream_t stream) {
  (void)in_sizes;
  (void)n_in;
  (void)out_size;
  (void)d_ws;
  (void)ws_size;
  const float4* pred = (const float4*)d_in[0];  // [B, Q, 4] f32
  const float4* gt = (const float4*)d_in[1];    // [B, G, 4] f32
  int* out = (int*)d_out;                       // [2 * B * G * N] int32
  atss_kernel<<<(GG / TT) * BB, TH, 0, stream>>>(pred, gt, out);
}